// Round 9
// baseline (110.542 us; speedup 1.0000x reference)
//
#include <hip/hip_runtime.h>
#include <hip/hip_bf16.h>

// GCN forward v4: out = PReLU(adj @ (seq @ W^T) + bias)
// B=256, N=512, IN_FT=OUT_FT=64. Output fp32.
// Two kernels, fill-like block independence in the agg stream:
//  fc  (R1-verified): sftT = (seq@W^T)^T bf16 [b][o][tok] -> d_ws (16 MB).
//  agg: 8192 independent blocks; each = ONE [16 x 512] fp32 adj chunk staged
//    via 2-KB-row global_load_lds into 32 KB LDS, single vmcnt(0)+barrier,
//    16 MFMAs, store, exit. No loop, no double-buffer, no counted vmcnt:
//    HBM queue depth comes from 5 blocks/CU at different phases.

#define BATCH 256
#define NTOK  512
#define INF   64
#define OUTF  64

typedef __attribute__((ext_vector_type(8))) __bf16 bf16x8;
typedef __attribute__((ext_vector_type(4))) __bf16 bf16x4;
typedef __attribute__((ext_vector_type(4))) float  f32x4;

typedef const __attribute__((address_space(1))) char GChar;
typedef __attribute__((address_space(3))) char LChar;

__device__ __forceinline__ bf16x8 load_cvt8(const float* __restrict__ p) {
    float4 lo = *(const float4*)p;
    float4 hi = *(const float4*)(p + 4);
    bf16x8 r;
    r[0] = (__bf16)lo.x; r[1] = (__bf16)lo.y; r[2] = (__bf16)lo.z; r[3] = (__bf16)lo.w;
    r[4] = (__bf16)hi.x; r[5] = (__bf16)hi.y; r[6] = (__bf16)hi.z; r[7] = (__bf16)hi.w;
    return r;
}

__device__ __forceinline__ bf16x8 pack8(float4 lo, float4 hi) {
    bf16x8 r;
    r[0] = (__bf16)lo.x; r[1] = (__bf16)lo.y; r[2] = (__bf16)lo.z; r[3] = (__bf16)lo.w;
    r[4] = (__bf16)hi.x; r[5] = (__bf16)hi.y; r[6] = (__bf16)hi.z; r[7] = (__bf16)hi.w;
    return r;
}

// ---------------- Kernel A: seq_fts^T = (seq @ W^T)^T -> bf16 (R1, verified)
__global__ __launch_bounds__(256) void GCN_fc_kernel(
        const float* __restrict__ seq, const float* __restrict__ W,
        __bf16* __restrict__ sftT) {
    int blk  = blockIdx.x;
    int b    = blk >> 3;
    int m0   = (blk & 7) * 64;
    int tid  = threadIdx.x;
    int wave = tid >> 6;
    int lane = tid & 63;
    int row16 = lane & 15;
    int g     = lane >> 4;
    int mbase = m0 + wave * 16;

    const float* sp = seq + ((size_t)b * NTOK + (mbase + row16)) * INF + g * 8;
    const float* wp = W + (size_t)row16 * INF + g * 8;

    f32x4 acc[4] = {};
#pragma unroll
    for (int ks = 0; ks < 2; ++ks) {
        bf16x8 a = load_cvt8(sp + ks * 32);
#pragma unroll
        for (int nt = 0; nt < 4; ++nt) {
            bf16x8 w8 = load_cvt8(wp + (size_t)nt * 16 * INF + ks * 32);
            acc[nt] = __builtin_amdgcn_mfma_f32_16x16x32_bf16(a, w8, acc[nt], 0, 0, 0);
        }
    }
#pragma unroll
    for (int nt = 0; nt < 4; ++nt) {
        int o = nt * 16 + row16;
        bf16x4 v;
        v[0] = (__bf16)acc[nt][0]; v[1] = (__bf16)acc[nt][1];
        v[2] = (__bf16)acc[nt][2]; v[3] = (__bf16)acc[nt][3];
        __bf16* dst = sftT + ((size_t)b * OUTF + o) * NTOK + mbase + g * 4;
        *(bf16x4*)dst = v;
    }
}

// ---------------- Kernel B: out = PReLU(adj @ seq_fts + bias) ----------------
// grid = 8192 (256 batches x 32 row-groups of 16), block = 256 (4 waves).
// One [16 rows x 512 k] fp32 chunk (32 KB LDS) per block. Waves split OUT_FT.
// XCD-chunked swizzle: a batch's 32 blocks land on one XCD -> its 64 KB sftT
// panel is L2-resident for the 32x reuse.
__global__ __launch_bounds__(256, 4) void GCN_agg_kernel(
        const float* __restrict__ adj, const __bf16* __restrict__ sftT,
        const float* __restrict__ bias, const float* __restrict__ alpha_p,
        float* __restrict__ out) {
    __shared__ float chunk[16 * 512];        // 32 KB -> 5 blocks/CU by LDS

    int p = blockIdx.x;
    int logical = (p & 7) * 1024 + (p >> 3); // 8192 % 8 == 0 -> bijective
    int b  = logical >> 5;
    int r0 = (logical & 31) * 16;            // this block's 16 adj rows

    int tid  = threadIdx.x;
    int wave = tid >> 6;                     // 0..3 = col-group
    int lane = tid & 63;
    int row16 = lane & 15;
    int g     = lane >> 4;                   // 0..3
    int rs    = row16 & 7;

    // ---- stage: 32 x global_load_lds (1 KB each), 8 per wave ----
    // idx = wave*8+i: row = idx>>1 (wave-uniform), half = idx&1. Lane fetches
    // swizzled 16-B slot (lane ^ (row&7)) within the row's 1-KB half so the
    // linear LDS holds LDS[row][s] = G[row][half*64 + (s ^ (row&7))].
    const float* gadj = adj + ((size_t)b * NTOK + r0) * NTOK;
#pragma unroll
    for (int i = 0; i < 8; ++i) {
        int idx  = wave * 8 + i;
        int row  = idx >> 1;
        int half = idx & 1;
        __builtin_amdgcn_global_load_lds(
            (GChar*)(gadj + (size_t)row * NTOK + half * 256 + (lane ^ (row & 7)) * 4),
            (LChar*)(chunk + idx * 256), 16, 0, 0);
    }

    // ---- B-frags from sftT (L2-hot panel): this wave's 16 cols, all K ----
    int orow = wave * 16 + row16;
    const __bf16* brow = sftT + ((size_t)b * OUTF + orow) * NTOK + g * 8;
    bf16x8 bbr[16];
#pragma unroll
    for (int t = 0; t < 16; ++t)
        bbr[t] = *(const bf16x8*)(brow + t * 32);

    float bv     = bias[orow];
    float alphav = alpha_p[0];

    asm volatile("s_waitcnt vmcnt(0)" ::: "memory");   // chunk + bbr landed
    __syncthreads();                                   // cross-wave rows visible

    // ---- compute: 16 rows x 16 cols, full K = 512 (16 MFMAs) ----
    f32x4 acc;
    acc[0] = bv; acc[1] = bv; acc[2] = bv; acc[3] = bv;
    int rowb = row16 * 512;                  // lane's A-row (2 KB) in the chunk
#pragma unroll
    for (int ks = 0; ks < 16; ++ks) {
        int s0 = (ks * 8 + g * 2) ^ rs;      // even base -> partner slot is ^1
        float4 f0 = *(const float4*)(chunk + rowb + s0 * 4);
        float4 f1 = *(const float4*)(chunk + rowb + (s0 ^ 1) * 4);
        bf16x8 a = pack8(f0, f1);
        acc = __builtin_amdgcn_mfma_f32_16x16x32_bf16(a, bbr[ks], acc, 0, 0, 0);
    }

    // ---- epilogue: PReLU + store (bias pre-loaded in acc); C/D row = g*4+j
    int m = r0 + g * 4;
    float* op = out + ((size_t)b * NTOK + m) * OUTF + orow;
#pragma unroll
    for (int j = 0; j < 4; ++j) {
        float v = acc[j];
        op[(size_t)j * OUTF] = (v >= 0.f) ? v : alphav * v;
    }
}

extern "C" void kernel_launch(void* const* d_in, const int* in_sizes, int n_in,
                              void* d_out, int out_size, void* d_ws, size_t ws_size,
                              hipStream_t stream) {
    const float* seq   = (const float*)d_in[0];
    const float* adj   = (const float*)d_in[1];
    const float* W     = (const float*)d_in[2];
    const float* bias  = (const float*)d_in[3];
    const float* alpha = (const float*)d_in[4];
    float* out = (float*)d_out;
    __bf16* sftT = (__bf16*)d_ws;            // 256*64*512*2 = 16 MB scratch

    GCN_fc_kernel<<<dim3(2048), dim3(256), 0, stream>>>(seq, W, sftT);
    GCN_agg_kernel<<<dim3(8192), dim3(256), 0, stream>>>(adj, sftT, bias, alpha, out);
}

// Round 10
// 110.442 us; speedup vs baseline: 1.0009x; 1.0009x over previous
//
#include <hip/hip_runtime.h>
#include <hip/hip_bf16.h>

// R10 = R6 (best, 72.1 us) VERBATIM + a pure-read BW probe appended.
// Probe: grid-strided float4 read of the whole adj (268 MB), max TLP,
// keep-alive asm, 4096 de-conflicted ws writes. dur_us - 72.1 = probe time.
// Decides: is the chip read ceiling ~6.3 TB/s (R6 structure at fault) or
// ~4.6 TB/s (R6 already at the read roofline)?

#define BATCH 256
#define NTOK  512
#define INF   64
#define OUTF  64

typedef __attribute__((ext_vector_type(8))) __bf16 bf16x8;
typedef __attribute__((ext_vector_type(4))) __bf16 bf16x4;
typedef __attribute__((ext_vector_type(4))) float  f32x4;

typedef const __attribute__((address_space(1))) char GChar;
typedef __attribute__((address_space(3))) char LChar;

__device__ __forceinline__ bf16x8 load_cvt8(const float* __restrict__ p) {
    float4 lo = *(const float4*)p;
    float4 hi = *(const float4*)(p + 4);
    bf16x8 r;
    r[0] = (__bf16)lo.x; r[1] = (__bf16)lo.y; r[2] = (__bf16)lo.z; r[3] = (__bf16)lo.w;
    r[4] = (__bf16)hi.x; r[5] = (__bf16)hi.y; r[6] = (__bf16)hi.z; r[7] = (__bf16)hi.w;
    return r;
}

__device__ __forceinline__ bf16x8 pack8(float4 lo, float4 hi) {
    bf16x8 r;
    r[0] = (__bf16)lo.x; r[1] = (__bf16)lo.y; r[2] = (__bf16)lo.z; r[3] = (__bf16)lo.w;
    r[4] = (__bf16)hi.x; r[5] = (__bf16)hi.y; r[6] = (__bf16)hi.z; r[7] = (__bf16)hi.w;
    return r;
}

__global__ __launch_bounds__(512, 2) void GCN_fused_kernel(
        const float* __restrict__ seq, const float* __restrict__ adj,
        const float* __restrict__ W, const float* __restrict__ bias,
        const float* __restrict__ alpha_p, float* __restrict__ out) {
    __shared__ float smem[32768];            // 128 KB

    int b    = blockIdx.x;
    int tid  = threadIdx.x;
    int wave = tid >> 6;                     // 0..7
    int lane = tid & 63;
    int row16 = lane & 15;
    int g     = lane >> 4;                   // 0..3
    int c     = wave & 3;                    // col-group: o in [c*16, c*16+16)
    int mt    = wave >> 2;                   // 0/1: rows [mt*16, mt*16+16) of chunk
    int rs    = row16 & 7;

    __bf16* sft = (__bf16*)smem;             // [64 o][512 k] bf16, slot-swizzled (lower 64 KB)
    float* buf0 = smem + 16384;              // upper 64 KB  (even chunks)
    float* buf1 = smem;                      // lower 64 KB, overlays sft (odd chunks)

    const float* gadj = adj + (size_t)b * NTOK * NTOK;

#define STAGE(dstf, rbase) do {                                                \
    _Pragma("unroll")                                                          \
    for (int i_ = 0; i_ < 8; ++i_) {                                           \
        int idx_  = wave * 8 + i_;                                             \
        int row_  = idx_ >> 1;                                                 \
        int half_ = idx_ & 1;                                                  \
        __builtin_amdgcn_global_load_lds(                                      \
            (GChar*)(gadj + (size_t)((rbase) + row_) * NTOK + half_ * 256      \
                     + (lane ^ (row_ & 7)) * 4),                               \
            (LChar*)((dstf) + idx_ * 256), 16, 0, 0);                          \
    }                                                                          \
} while (0)

    STAGE(buf0, 0);                          // chunk 0 in flight during phase 1

    // ================= Phase 1: sft[o][k] = (seq @ W^T)^T ===================
    {
        int mb = wave * 64;
        bf16x8 wf[4][2];
#pragma unroll
        for (int nt = 0; nt < 4; ++nt)
#pragma unroll
            for (int ks = 0; ks < 2; ++ks)
                wf[nt][ks] = load_cvt8(W + (size_t)(nt * 16 + row16) * INF + ks * 32 + g * 8);

#pragma unroll
        for (int mt2 = 0; mt2 < 4; ++mt2) {
            f32x4 pa[4] = {};
#pragma unroll
            for (int ks = 0; ks < 2; ++ks) {
                bf16x8 af = load_cvt8(seq + ((size_t)b * NTOK + mb + mt2 * 16 + row16) * INF + ks * 32 + g * 8);
#pragma unroll
                for (int nt = 0; nt < 4; ++nt)
                    pa[nt] = __builtin_amdgcn_mfma_f32_16x16x32_bf16(af, wf[nt][ks], pa[nt], 0, 0, 0);
            }
#pragma unroll
            for (int nt = 0; nt < 4; ++nt) {
                int o    = nt * 16 + row16;
                int ktok = mb + mt2 * 16 + g * 4;
                int sw   = (ktok >> 3) ^ (o & 7);
                bf16x4 v;
                v[0] = (__bf16)pa[nt][0]; v[1] = (__bf16)pa[nt][1];
                v[2] = (__bf16)pa[nt][2]; v[3] = (__bf16)pa[nt][3];
                *(bf16x4*)((char*)sft + (size_t)o * 1024 + sw * 16 + (ktok & 7) * 2) = v;
            }
        }
    }
    int orow     = c * 16 + row16;
    float bv     = bias[orow];
    float alphav = alpha_p[0];
    __syncthreads();

    // ============ Redistribute: B-frags, this wave's 16 cols, all K =========
    bf16x8 bbr[16];
#pragma unroll
    for (int t = 0; t < 16; ++t) {
        int sw = ((t << 2) + g) ^ rs;
        bbr[t] = *(const bf16x8*)((const char*)sft + (size_t)orow * 1024 + sw * 16);
    }
    __syncthreads();   // also drains all prior vmem incl. chunk-0 stage

    // ================= Phase 2: 16 chunks of [32 rows x 512 k] ==============
#pragma unroll 1
    for (int it = 0; it < 16; ++it) {
        float* cur = (it & 1) ? buf1 : buf0;
        float* nxt = (it & 1) ? buf0 : buf1;

        if (it > 0) {
            __builtin_amdgcn_sched_barrier(0);
            __builtin_amdgcn_s_barrier();
            __builtin_amdgcn_sched_barrier(0);
        }
        if (it < 15) STAGE(nxt, (it + 1) * 32);
        __builtin_amdgcn_sched_barrier(0);
        if (it == 0)       asm volatile("s_waitcnt vmcnt(8)"  ::: "memory");
        else if (it < 15)  asm volatile("s_waitcnt vmcnt(12)" ::: "memory");
        else               asm volatile("s_waitcnt vmcnt(4)"  ::: "memory");
        __builtin_amdgcn_sched_barrier(0);
        __builtin_amdgcn_s_barrier();
        __builtin_amdgcn_sched_barrier(0);

        f32x4 acc;
        acc[0] = bv; acc[1] = bv; acc[2] = bv; acc[3] = bv;
        int rowb = (mt * 16 + row16) * 512;
#pragma unroll
        for (int ks = 0; ks < 16; ++ks) {
            int s0 = (ks * 8 + g * 2) ^ rs;
            float4 f0 = *(const float4*)(cur + rowb + s0 * 4);
            float4 f1 = *(const float4*)(cur + rowb + (s0 ^ 1) * 4);
            bf16x8 a = pack8(f0, f1);
            acc = __builtin_amdgcn_mfma_f32_16x16x32_bf16(a, bbr[ks], acc, 0, 0, 0);
        }

        int m = it * 32 + mt * 16 + g * 4;
        float* op = out + ((size_t)b * NTOK + m) * OUTF + orow;
#pragma unroll
        for (int j = 0; j < 4; ++j) {
            float v = acc[j];
            op[(size_t)j * OUTF] = (v >= 0.f) ? v : alphav * v;
        }
    }
#undef STAGE
}

// ---------------- READ-BW PROBE: grid-strided float4 stream of adj ----------
// 2048 blocks x 256 thr = 524288 threads x 32 iters x 16 B = 268 MB (exact).
// Perfectly coalesced; stride between iters = 8 MB. Keep-alive via asm;
// only threads < 4096 write (to d_ws, which the main kernel doesn't use).
__global__ __launch_bounds__(256) void read_probe_kernel(
        const float4* __restrict__ adj4, float* __restrict__ ws) {
    size_t i = (size_t)blockIdx.x * 256 + threadIdx.x;   // 0..524287
    float4 s = make_float4(0.f, 0.f, 0.f, 0.f);
#pragma unroll
    for (int it = 0; it < 32; ++it) {
        float4 v = adj4[i + (size_t)it * 524288];
        s.x += v.x; s.y += v.y; s.z += v.z; s.w += v.w;
    }
    // keep the loads live even for non-writing threads (rule #17)
    asm volatile("" :: "v"(s.x), "v"(s.y), "v"(s.z), "v"(s.w));
    if (i < 4096) ws[i] = s.x + s.y + s.z + s.w;
}

extern "C" void kernel_launch(void* const* d_in, const int* in_sizes, int n_in,
                              void* d_out, int out_size, void* d_ws, size_t ws_size,
                              hipStream_t stream) {
    const float* seq   = (const float*)d_in[0];
    const float* adj   = (const float*)d_in[1];
    const float* W     = (const float*)d_in[2];
    const float* bias  = (const float*)d_in[3];
    const float* alpha = (const float*)d_in[4];
    float* out = (float*)d_out;

    GCN_fused_kernel<<<dim3(BATCH), dim3(512), 0, stream>>>(seq, adj, W, bias, alpha, out);
    read_probe_kernel<<<dim3(2048), dim3(256), 0, stream>>>((const float4*)adj, (float*)d_ws);
}

// Round 11
// 71.704 us; speedup vs baseline: 1.5416x; 1.5402x over previous
//
#include <hip/hip_runtime.h>
#include <hip/hip_bf16.h>

// GCN forward FUSED v4: out = PReLU(adj @ (seq @ W^T) + bias)
// B=256, N=512, F=64. grid=256 (1 block/batch/CU), block=512 (8 waves), 128KB LDS.
// R10 probe: pure VGPR reads hit 7.0 TB/s; R6 (global_load_lds) = 4.65 TB/s.
// This round: SAME R6 schedule, staging switched to reg-stage (coalesced
// float4 global->VGPR, probe-identical pattern) + swizzled ds_write_b128.
// Counted vmcnt keeps next chunk's loads in flight; ONE barrier per chunk.

#define BATCH 256
#define NTOK  512
#define INF   64
#define OUTF  64

typedef __attribute__((ext_vector_type(8))) __bf16 bf16x8;
typedef __attribute__((ext_vector_type(4))) __bf16 bf16x4;
typedef __attribute__((ext_vector_type(4))) float  f32x4;

__device__ __forceinline__ bf16x8 load_cvt8(const float* __restrict__ p) {
    float4 lo = *(const float4*)p;
    float4 hi = *(const float4*)(p + 4);
    bf16x8 r;
    r[0] = (__bf16)lo.x; r[1] = (__bf16)lo.y; r[2] = (__bf16)lo.z; r[3] = (__bf16)lo.w;
    r[4] = (__bf16)hi.x; r[5] = (__bf16)hi.y; r[6] = (__bf16)hi.z; r[7] = (__bf16)hi.w;
    return r;
}

__device__ __forceinline__ bf16x8 pack8(float4 lo, float4 hi) {
    bf16x8 r;
    r[0] = (__bf16)lo.x; r[1] = (__bf16)lo.y; r[2] = (__bf16)lo.z; r[3] = (__bf16)lo.w;
    r[4] = (__bf16)hi.x; r[5] = (__bf16)hi.y; r[6] = (__bf16)hi.z; r[7] = (__bf16)hi.w;
    return r;
}

__global__ __launch_bounds__(512, 2) void GCN_fused_kernel(
        const float* __restrict__ seq, const float* __restrict__ adj,
        const float* __restrict__ W, const float* __restrict__ bias,
        const float* __restrict__ alpha_p, float* __restrict__ out) {
    __shared__ float smem[32768];            // 128 KB

    int b    = blockIdx.x;
    int tid  = threadIdx.x;
    int wave = tid >> 6;                     // 0..7
    int lane = tid & 63;
    int row16 = lane & 15;
    int g     = lane >> 4;                   // 0..3
    int c     = wave & 3;                    // col-group: o in [c*16, c*16+16)
    int mt    = wave >> 2;                   // 0/1: rows [mt*16,+16) of chunk
    int rs    = row16 & 7;

    __bf16* sft = (__bf16*)smem;             // [64 o][512 k] bf16 (lower 64 KB)
    float* buf0 = smem + 16384;              // even chunks (upper 64 KB)
    float* buf1 = smem;                      // odd chunks (overlays sft)

    const float* gadj = adj + (size_t)b * NTOK * NTOK;

    // Per-wave staging: 8 x 1-KB fully-coalesced float4 loads (LINEAR source).
    // idx = wave*8+i: row = idx>>1, half = idx&1; lane reads 16-B slot `lane`.
    // Swizzle applied at ds_write: LDS slot = lane ^ (row&7)  (same involution
    // the compute-side ds_read uses: s0 = (ks*8+g*2) ^ rs).
#define GLOAD(RG, rbase) do {                                                  \
    _Pragma("unroll")                                                          \
    for (int i_ = 0; i_ < 8; ++i_) {                                           \
        int idx_ = wave * 8 + i_;                                              \
        (RG)[i_] = *(const f32x4*)(gadj + (size_t)((rbase) + (idx_ >> 1)) * NTOK \
                                   + (idx_ & 1) * 256 + lane * 4);             \
    }                                                                          \
} while (0)

#define DSWRITE(RG, dstf) do {                                                 \
    _Pragma("unroll")                                                          \
    for (int i_ = 0; i_ < 8; ++i_) {                                           \
        int idx_ = wave * 8 + i_;                                              \
        int row_ = idx_ >> 1;                                                  \
        *(f32x4*)((dstf) + idx_ * 256 + ((lane ^ (row_ & 7)) << 2)) = (RG)[i_];\
    }                                                                          \
} while (0)

#define COMPUTE(CIDX, cur) do {                                                \
    f32x4 acc; acc[0] = bv; acc[1] = bv; acc[2] = bv; acc[3] = bv;             \
    int rowb_ = (mt * 16 + row16) * 512;                                       \
    _Pragma("unroll")                                                          \
    for (int ks_ = 0; ks_ < 16; ++ks_) {                                       \
        int s0_ = (ks_ * 8 + g * 2) ^ rs;                                      \
        float4 f0_ = *(const float4*)((cur) + rowb_ + s0_ * 4);                \
        float4 f1_ = *(const float4*)((cur) + rowb_ + (s0_ ^ 1) * 4);          \
        bf16x8 a_ = pack8(f0_, f1_);                                           \
        acc = __builtin_amdgcn_mfma_f32_16x16x32_bf16(a_, bbr[ks_], acc, 0, 0, 0); \
    }                                                                          \
    int m_ = (CIDX) * 32 + mt * 16 + g * 4;                                    \
    float* op_ = out + ((size_t)b * NTOK + m_) * OUTF + orow;                  \
    _Pragma("unroll")                                                          \
    for (int j_ = 0; j_ < 4; ++j_) {                                           \
        float v_ = acc[j_];                                                    \
        op_[(size_t)j_ * OUTF] = (v_ >= 0.f) ? v_ : alphav * v_;               \
    }                                                                          \
} while (0)

    f32x4 ra[8], rb[8];
    GLOAD(ra, 0);                            // chunk 0 prefetch, hides under phase 1
    __builtin_amdgcn_sched_barrier(0);

    // ================= Phase 1: sft[o][k] = (seq @ W^T)^T ===================
    {
        int mb = wave * 64;
        bf16x8 wf[4][2];
#pragma unroll
        for (int nt = 0; nt < 4; ++nt)
#pragma unroll
            for (int ks = 0; ks < 2; ++ks)
                wf[nt][ks] = load_cvt8(W + (size_t)(nt * 16 + row16) * INF + ks * 32 + g * 8);

#pragma unroll
        for (int mt2 = 0; mt2 < 4; ++mt2) {
            f32x4 pa[4] = {};
#pragma unroll
            for (int ks = 0; ks < 2; ++ks) {
                bf16x8 af = load_cvt8(seq + ((size_t)b * NTOK + mb + mt2 * 16 + row16) * INF + ks * 32 + g * 8);
#pragma unroll
                for (int nt = 0; nt < 4; ++nt)
                    pa[nt] = __builtin_amdgcn_mfma_f32_16x16x32_bf16(af, wf[nt][ks], pa[nt], 0, 0, 0);
            }
            // D: col(o)=row16-part, row(tok)=g*4+reg. Swizzled bf16 store:
            // 16-B slot s = k>>3 stored at s ^ (o&7), within-slot offset k&7.
#pragma unroll
            for (int nt = 0; nt < 4; ++nt) {
                int o    = nt * 16 + row16;
                int ktok = mb + mt2 * 16 + g * 4;
                int sw   = (ktok >> 3) ^ (o & 7);
                bf16x4 v;
                v[0] = (__bf16)pa[nt][0]; v[1] = (__bf16)pa[nt][1];
                v[2] = (__bf16)pa[nt][2]; v[3] = (__bf16)pa[nt][3];
                *(bf16x4*)((char*)sft + (size_t)o * 1024 + sw * 16 + (ktok & 7) * 2) = v;
            }
        }
    }
    int orow     = c * 16 + row16;
    float bv     = bias[orow];
    float alphav = alpha_p[0];
    __syncthreads();

    // ============ Redistribute: B-frags, this wave's 16 cols, all K =========
    bf16x8 bbr[16];
#pragma unroll
    for (int t = 0; t < 16; ++t) {
        int sw = ((t << 2) + g) ^ rs;
        bbr[t] = *(const bf16x8*)((const char*)sft + (size_t)orow * 1024 + sw * 16);
    }
    __syncthreads();                         // sft reads done; buf1 reusable

    // ================= Phase 2: 16 chunks of [32 rows x 512 k] ==============
    // Per double-iteration: even chunk e=2*it2 (ra -> buf0), odd o=e+1 (rb -> buf1).
    // Buffer-overwrite vs readers separated by exactly one barrier each (audited).
#pragma unroll 1
    for (int it2 = 0; it2 < 8; ++it2) {
        int e = it2 * 2, o = e + 1;

        // ---- even body: chunk e (regs ra) -> buf0 ----
        GLOAD(rb, o * 32);                   // issue odd chunk's loads
        __builtin_amdgcn_sched_barrier(0);
        // outstanding: [ra 8][(it2>0: stores 4)][rb 8] -> drain ra
        if (it2 == 0) asm volatile("s_waitcnt vmcnt(8)"  ::: "memory");
        else          asm volatile("s_waitcnt vmcnt(12)" ::: "memory");
        __builtin_amdgcn_sched_barrier(0);
        DSWRITE(ra, buf0);
        asm volatile("s_waitcnt lgkmcnt(0)" ::: "memory");
        __builtin_amdgcn_sched_barrier(0);
        __builtin_amdgcn_s_barrier();
        __builtin_amdgcn_sched_barrier(0);
        COMPUTE(e, buf0);

        // ---- odd body: chunk o (regs rb) -> buf1 ----
        if (it2 < 7) GLOAD(ra, (e + 2) * 32);
        __builtin_amdgcn_sched_barrier(0);
        // outstanding: [rb 8][stores 4][(it2<7: ra 8)] -> drain rb
        if (it2 < 7) asm volatile("s_waitcnt vmcnt(12)" ::: "memory");
        else         asm volatile("s_waitcnt vmcnt(4)"  ::: "memory");
        __builtin_amdgcn_sched_barrier(0);
        DSWRITE(rb, buf1);
        asm volatile("s_waitcnt lgkmcnt(0)" ::: "memory");
        __builtin_amdgcn_sched_barrier(0);
        __builtin_amdgcn_s_barrier();
        __builtin_amdgcn_sched_barrier(0);
        COMPUTE(o, buf1);
    }
#undef GLOAD
#undef DSWRITE
#undef COMPUTE
}

extern "C" void kernel_launch(void* const* d_in, const int* in_sizes, int n_in,
                              void* d_out, int out_size, void* d_ws, size_t ws_size,
                              hipStream_t stream) {
    const float* seq   = (const float*)d_in[0];
    const float* adj   = (const float*)d_in[1];
    const float* W     = (const float*)d_in[2];
    const float* bias  = (const float*)d_in[3];
    const float* alpha = (const float*)d_in[4];
    float* out = (float*)d_out;

    GCN_fused_kernel<<<dim3(BATCH), dim3(512), 0, stream>>>(seq, adj, W, bias, alpha, out);
}

// Round 12
// 70.752 us; speedup vs baseline: 1.5624x; 1.0135x over previous
//
#include <hip/hip_runtime.h>
#include <hip/hip_bf16.h>

// GCN forward FUSED v5: out = PReLU(adj @ (seq @ W^T) + bias)
// B=256, N=512, F=64. grid=256 (1 block/batch/CU), block=512 (8 waves), 128KB LDS.
// R10 probe: chip sustains 7.0 TB/s pure reads; R6/R11 structures = 4.65 TB/s.
// R11 lesson: staging mechanism irrelevant -> limiter is HBM duty cycle
// (depth-1 prefetch: 64 KB/CU must land in ~1.3us compute phase, needs 2.34us).
// v5: DEPTH-2 prefetch via 3 register groups, 16 manually-instantiated bodies
// (static reg indexing), issue chunk i+2 before COMPUTE(i). vmcnt audited.

#define BATCH 256
#define NTOK  512
#define INF   64
#define OUTF  64

typedef __attribute__((ext_vector_type(8))) __bf16 bf16x8;
typedef __attribute__((ext_vector_type(4))) __bf16 bf16x4;
typedef __attribute__((ext_vector_type(4))) float  f32x4;

__device__ __forceinline__ bf16x8 load_cvt8(const float* __restrict__ p) {
    float4 lo = *(const float4*)p;
    float4 hi = *(const float4*)(p + 4);
    bf16x8 r;
    r[0] = (__bf16)lo.x; r[1] = (__bf16)lo.y; r[2] = (__bf16)lo.z; r[3] = (__bf16)lo.w;
    r[4] = (__bf16)hi.x; r[5] = (__bf16)hi.y; r[6] = (__bf16)hi.z; r[7] = (__bf16)hi.w;
    return r;
}

__device__ __forceinline__ bf16x8 pack8(float4 lo, float4 hi) {
    bf16x8 r;
    r[0] = (__bf16)lo.x; r[1] = (__bf16)lo.y; r[2] = (__bf16)lo.z; r[3] = (__bf16)lo.w;
    r[4] = (__bf16)hi.x; r[5] = (__bf16)hi.y; r[6] = (__bf16)hi.z; r[7] = (__bf16)hi.w;
    return r;
}

__global__ __launch_bounds__(512, 2) void GCN_fused_kernel(
        const float* __restrict__ seq, const float* __restrict__ adj,
        const float* __restrict__ W, const float* __restrict__ bias,
        const float* __restrict__ alpha_p, float* __restrict__ out) {
    __shared__ float smem[32768];            // 128 KB

    int b    = blockIdx.x;
    int tid  = threadIdx.x;
    int wave = tid >> 6;                     // 0..7
    int lane = tid & 63;
    int row16 = lane & 15;
    int g     = lane >> 4;                   // 0..3
    int c     = wave & 3;                    // col-group: o in [c*16, c*16+16)
    int mt    = wave >> 2;                   // 0/1: rows [mt*16,+16) of chunk
    int rs    = row16 & 7;

    __bf16* sft = (__bf16*)smem;             // [64 o][512 k] bf16 (lower 64 KB)
    float* buf0 = smem + 16384;              // even chunks (upper 64 KB)
    float* buf1 = smem;                      // odd chunks (overlays sft)

    const float* gadj = adj + (size_t)b * NTOK * NTOK;

    // Per-wave staging: 8 x 1-KB fully-coalesced float4 loads (LINEAR source).
    // idx = wave*8+i: row = idx>>1, half = idx&1; lane reads 16-B slot `lane`.
    // Swizzle applied at ds_write: LDS slot = lane ^ (row&7) (same involution
    // as compute-side ds_read: s0 = (ks*8+g*2) ^ rs).
#define GLOAD(RG, rbase) do {                                                  \
    _Pragma("unroll")                                                          \
    for (int i_ = 0; i_ < 8; ++i_) {                                           \
        int idx_ = wave * 8 + i_;                                              \
        (RG)[i_] = *(const f32x4*)(gadj + (size_t)((rbase) + (idx_ >> 1)) * NTOK \
                                   + (idx_ & 1) * 256 + lane * 4);             \
    }                                                                          \
} while (0)

#define DSWRITE(RG, dstf) do {                                                 \
    _Pragma("unroll")                                                          \
    for (int i_ = 0; i_ < 8; ++i_) {                                           \
        int idx_ = wave * 8 + i_;                                              \
        int row_ = idx_ >> 1;                                                  \
        *(f32x4*)((dstf) + idx_ * 256 + ((lane ^ (row_ & 7)) << 2)) = (RG)[i_];\
    }                                                                          \
} while (0)

#define COMPUTE(CIDX, cur) do {                                                \
    f32x4 acc; acc[0] = bv; acc[1] = bv; acc[2] = bv; acc[3] = bv;             \
    int rowb_ = (mt * 16 + row16) * 512;                                       \
    _Pragma("unroll")                                                          \
    for (int ks_ = 0; ks_ < 16; ++ks_) {                                       \
        int s0_ = (ks_ * 8 + g * 2) ^ rs;                                      \
        float4 f0_ = *(const float4*)((cur) + rowb_ + s0_ * 4);                \
        float4 f1_ = *(const float4*)((cur) + rowb_ + (s0_ ^ 1) * 4);          \
        bf16x8 a_ = pack8(f0_, f1_);                                           \
        acc = __builtin_amdgcn_mfma_f32_16x16x32_bf16(a_, bbr[ks_], acc, 0, 0, 0); \
    }                                                                          \
    int m_ = (CIDX) * 32 + mt * 16 + g * 4;                                    \
    float* op_ = out + ((size_t)b * NTOK + m_) * OUTF + orow;                  \
    _Pragma("unroll")                                                          \
    for (int j_ = 0; j_ < 4; ++j_) {                                           \
        float v_ = acc[j_];                                                    \
        op_[(size_t)j_ * OUTF] = (v_ >= 0.f) ? v_ : alphav * v_;               \
    }                                                                          \
} while (0)

    // One phase-2 body. Steady-state outstanding vmem at the drain (in-order):
    // [G(i) 8][S(i-2) 4][G(i+1) 8][S(i-1) 4] = 24 -> vmcnt(16) retires G(i)
    // exactly. i=15: [G(15) 8][S 4][S 4] = 16 -> vmcnt(8).
#define BODY(CIDX, CUR, GC, DOLOAD, GN, WAITN) do {                            \
    asm volatile("s_waitcnt vmcnt(" #WAITN ")" ::: "memory");                  \
    __builtin_amdgcn_sched_barrier(0);                                         \
    DSWRITE(GC, CUR);                                                          \
    asm volatile("s_waitcnt lgkmcnt(0)" ::: "memory");                         \
    __builtin_amdgcn_sched_barrier(0);                                         \
    __builtin_amdgcn_s_barrier();                                              \
    __builtin_amdgcn_sched_barrier(0);                                         \
    if (DOLOAD) { GLOAD(GN, ((CIDX) + 2) * 32); }                              \
    __builtin_amdgcn_sched_barrier(0);                                         \
    COMPUTE(CIDX, CUR);                                                        \
} while (0)

    f32x4 g0[8], g1[8], g2[8];
    GLOAD(g0, 0);                            // chunks 0,1 prefetch under phase 1
    GLOAD(g1, 32);
    __builtin_amdgcn_sched_barrier(0);

    // ================= Phase 1: sft[o][k] = (seq @ W^T)^T ===================
    {
        int mb = wave * 64;
        bf16x8 wf[4][2];
#pragma unroll
        for (int nt = 0; nt < 4; ++nt)
#pragma unroll
            for (int ks = 0; ks < 2; ++ks)
                wf[nt][ks] = load_cvt8(W + (size_t)(nt * 16 + row16) * INF + ks * 32 + g * 8);

#pragma unroll
        for (int mt2 = 0; mt2 < 4; ++mt2) {
            f32x4 pa[4] = {};
#pragma unroll
            for (int ks = 0; ks < 2; ++ks) {
                bf16x8 af = load_cvt8(seq + ((size_t)b * NTOK + mb + mt2 * 16 + row16) * INF + ks * 32 + g * 8);
#pragma unroll
                for (int nt = 0; nt < 4; ++nt)
                    pa[nt] = __builtin_amdgcn_mfma_f32_16x16x32_bf16(af, wf[nt][ks], pa[nt], 0, 0, 0);
            }
            // D: col(o)=row16-part, row(tok)=g*4+reg. Swizzled bf16 store:
            // 16-B slot s = k>>3 stored at s ^ (o&7), within-slot offset k&7.
#pragma unroll
            for (int nt = 0; nt < 4; ++nt) {
                int o    = nt * 16 + row16;
                int ktok = mb + mt2 * 16 + g * 4;
                int sw   = (ktok >> 3) ^ (o & 7);
                bf16x4 v;
                v[0] = (__bf16)pa[nt][0]; v[1] = (__bf16)pa[nt][1];
                v[2] = (__bf16)pa[nt][2]; v[3] = (__bf16)pa[nt][3];
                *(bf16x4*)((char*)sft + (size_t)o * 1024 + sw * 16 + (ktok & 7) * 2) = v;
            }
        }
    }
    int orow     = c * 16 + row16;
    float bv     = bias[orow];
    float alphav = alpha_p[0];
    __syncthreads();

    // ============ Redistribute: B-frags, this wave's 16 cols, all K =========
    bf16x8 bbr[16];
#pragma unroll
    for (int t = 0; t < 16; ++t) {
        int sw = ((t << 2) + g) ^ rs;
        bbr[t] = *(const bf16x8*)((const char*)sft + (size_t)orow * 1024 + sw * 16);
    }
    __syncthreads();   // drains all vmem (incl. g0/g1 prefetch); buf1 reusable

    // ================= Phase 2: 16 chunks, depth-2 pipeline =================
    // chunk i lives in group i%3; iter i issues chunk i+2 into (i+2)%3.
    BODY( 0, buf0, g0, 1, g2, 16);
    BODY( 1, buf1, g1, 1, g0, 16);
    BODY( 2, buf0, g2, 1, g1, 16);
    BODY( 3, buf1, g0, 1, g2, 16);
    BODY( 4, buf0, g1, 1, g0, 16);
    BODY( 5, buf1, g2, 1, g1, 16);
    BODY( 6, buf0, g0, 1, g2, 16);
    BODY( 7, buf1, g1, 1, g0, 16);
    BODY( 8, buf0, g2, 1, g1, 16);
    BODY( 9, buf1, g0, 1, g2, 16);
    BODY(10, buf0, g1, 1, g0, 16);
    BODY(11, buf1, g2, 1, g1, 16);
    BODY(12, buf0, g0, 1, g2, 16);
    BODY(13, buf1, g1, 1, g0, 16);
    BODY(14, buf0, g2, 0, g0, 16);
    BODY(15, buf1, g0, 0, g0,  8);
#undef BODY
#undef GLOAD
#undef DSWRITE
#undef COMPUTE
}

extern "C" void kernel_launch(void* const* d_in, const int* in_sizes, int n_in,
                              void* d_out, int out_size, void* d_ws, size_t ws_size,
                              hipStream_t stream) {
    const float* seq   = (const float*)d_in[0];
    const float* adj   = (const float*)d_in[1];
    const float* W     = (const float*)d_in[2];
    const float* bias  = (const float*)d_in[3];
    const float* alpha = (const float*)d_in[4];
    float* out = (float*)d_out;

    GCN_fused_kernel<<<dim3(BATCH), dim3(512), 0, stream>>>(seq, adj, W, bias, alpha, out);
}